// Round 1
// baseline (454.067 us; speedup 1.0000x reference)
//
#include <hip/hip_runtime.h>
#include <hip/hip_bf16.h>

// WinMSA fused kernel for MI355X (gfx950).
// B=64, WN=64 windows, S=49 tokens (pad 64), C=192, H=6 heads, D=32.
// One block per window, 512 threads (8 waves). bf16 MFMA 16x16x32 everywhere.

typedef __attribute__((ext_vector_type(4))) float f32x4;
typedef __attribute__((ext_vector_type(8))) short bf16x8;
typedef __attribute__((ext_vector_type(4))) unsigned short u16x4;

#define SCALE 0.17677669529663689f  // 32^-0.5

__device__ __forceinline__ unsigned short f2bf(float f) {
  union { float f; unsigned int u; } v; v.f = f;
  return (unsigned short)((v.u + 0x7FFFu + ((v.u >> 16) & 1u)) >> 16);  // RNE
}

// Pre-kernel: transpose weights to bf16 [out][in] so block staging is flat/coalesced.
__global__ void wprep(const float* __restrict__ Wqkv, const float* __restrict__ Wo,
                      unsigned short* __restrict__ WqkvT, unsigned short* __restrict__ WoT) {
  int i = blockIdx.x * 256 + threadIdx.x;
  if (i < 576 * 192) { int n = i / 192, k = i % 192; WqkvT[i] = f2bf(Wqkv[k * 576 + n]); }
  if (i < 192 * 192) { int n = i / 192, k = i % 192; WoT[i]   = f2bf(Wo[k * 192 + n]); }
}

__global__ __launch_bounds__(512, 2)
void winmsa(const float* __restrict__ X, const unsigned short* __restrict__ WqkvT,
            const float* __restrict__ bqkv, const unsigned short* __restrict__ WoT,
            const float* __restrict__ bo, const float* __restrict__ btab,
            float* __restrict__ out) {
  // Row stride 200 ushorts (400 B) -> 16-lane row reads hit banks 4c%32: 2-way (free).
  __shared__ __align__(16) unsigned short Xs[64 * 200];   // X bf16; reused as attn-out
  __shared__ __align__(16) unsigned short WtC[64 * 200];  // W chunk; overlaid: P scratch + bias table
  __shared__ __align__(16) unsigned short Qs[64 * 200];
  __shared__ __align__(16) unsigned short Ks[64 * 200];
  __shared__ __align__(16) unsigned short Vt[192 * 72];   // V transposed [d][token]

  const int tid  = threadIdx.x;
  const int w8   = tid >> 6;      // wave 0..7
  const int lane = tid & 63;
  const int g    = lane >> 4;     // 0..3
  const int c    = lane & 15;     // 0..15
  const int mt   = w8 & 3;        // M-tile (16 query rows)
  const int half = w8 >> 2;       // N-half split
  const int wb   = blockIdx.x;    // window id 0..4095

  // ---- Phase 0: zero pad rows 49..63 of Xs, stage X f32 -> bf16 ----
  for (int i = tid; i < 1500; i += 512) ((unsigned int*)(Xs + 49 * 200))[i] = 0u;
  const float* Xg = X + (size_t)wb * 9408;
  for (int j = tid; j < 2352; j += 512) {           // 2352 float4 = 49*192 floats
    f32x4 x4 = ((const f32x4*)Xg)[j];
    int f = j * 4, row = f / 192, col = f % 192;
    u16x4 p;
    p[0] = f2bf(x4[0]); p[1] = f2bf(x4[1]); p[2] = f2bf(x4[2]); p[3] = f2bf(x4[3]);
    *(u16x4*)(Xs + row * 200 + col) = p;
  }
  __syncthreads();

  // ---- Phase A: QKV = X @ Wqkv + b, in 9 chunks of 64 output cols ----
  for (int nc = 0; nc < 9; ++nc) {
    const unsigned short* Wg = WqkvT + nc * (64 * 192);
    #pragma unroll
    for (int jj = 0; jj < 3; ++jj) {                // 1536 x 16B / 512 threads
      int j = tid + jj * 512;
      uint4 v = ((const uint4*)Wg)[j];
      int row = j / 24, kc = j % 24;
      *(uint4*)(WtC + row * 200 + kc * 8) = v;
    }
    __syncthreads();

    f32x4 a0 = {0.f, 0.f, 0.f, 0.f}, a1 = {0.f, 0.f, 0.f, 0.f};
    const unsigned short* ar = Xs + (mt * 16 + c) * 200;
    const unsigned short* b0 = WtC + (half * 32 + c) * 200;
    const unsigned short* b1 = b0 + 16 * 200;
    #pragma unroll
    for (int ks = 0; ks < 6; ++ks) {                // K = 192
      int ko = ks * 32 + g * 8;
      bf16x8 av  = *(const bf16x8*)(ar + ko);
      bf16x8 bv0 = *(const bf16x8*)(b0 + ko);
      bf16x8 bv1 = *(const bf16x8*)(b1 + ko);
      a0 = __builtin_amdgcn_mfma_f32_16x16x32_bf16(av, bv0, a0, 0, 0, 0);
      a1 = __builtin_amdgcn_mfma_f32_16x16x32_bf16(av, bv1, a1, 0, 0, 0);
    }
    // Scatter D (col=lane&15, row=4g+reg) into Q / K (row-major) or V (transposed)
    #pragma unroll
    for (int i = 0; i < 2; ++i) {
      f32x4 acc = i ? a1 : a0;
      int gcol = nc * 64 + half * 32 + i * 16 + c;  // 0..575, region uniform per (nc,half,i)
      float bias = bqkv[gcol];
      int rb = mt * 16 + g * 4;
      if (gcol < 192) {
        #pragma unroll
        for (int r = 0; r < 4; ++r) Qs[(rb + r) * 200 + gcol] = f2bf(acc[r] + bias);
      } else if (gcol < 384) {
        #pragma unroll
        for (int r = 0; r < 4; ++r) Ks[(rb + r) * 200 + gcol - 192] = f2bf(acc[r] + bias);
      } else {
        u16x4 pv;
        #pragma unroll
        for (int r = 0; r < 4; ++r) pv[r] = f2bf(acc[r] + bias);
        *(u16x4*)(Vt + (gcol - 384) * 72 + rb) = pv;  // 4 consecutive tokens packed
      }
    }
    __syncthreads();
  }

  // ---- Phase B: attention. Overlay WtC: [0,9216) ushort = per-wave P scratch, bias at +9216 ----
  float* biasF = (float*)(WtC + 9216);
  for (int j = tid; j < 1014; j += 512) biasF[j] = btab[j];
  __syncthreads();

  unsigned short* Psw = WtC + w8 * 1152;  // [16][72] bf16 per wave
  const int qrow = mt * 16;

  for (int hi = 0; hi < 3; ++hi) {
    int h = half * 3 + hi;                 // waves 0-3: h 0..2, waves 4-7: h 3..5
    // QK^T: A = Q rows, B = K^T (read K rows, d-contiguous). One K-step (D=32).
    bf16x8 aq = *(const bf16x8*)(Qs + (qrow + c) * 200 + h * 32 + g * 8);
    f32x4 z = {0.f, 0.f, 0.f, 0.f};
    f32x4 s0 = __builtin_amdgcn_mfma_f32_16x16x32_bf16(aq, *(const bf16x8*)(Ks + (c) * 200 + h * 32 + g * 8), z, 0, 0, 0);
    f32x4 s1 = __builtin_amdgcn_mfma_f32_16x16x32_bf16(aq, *(const bf16x8*)(Ks + (16 + c) * 200 + h * 32 + g * 8), z, 0, 0, 0);
    f32x4 s2 = __builtin_amdgcn_mfma_f32_16x16x32_bf16(aq, *(const bf16x8*)(Ks + (32 + c) * 200 + h * 32 + g * 8), z, 0, 0, 0);
    f32x4 s3 = __builtin_amdgcn_mfma_f32_16x16x32_bf16(aq, *(const bf16x8*)(Ks + (48 + c) * 200 + h * 32 + g * 8), z, 0, 0, 0);

    auto logit = [&](float sv, int col, int r) -> float {
      if (r < 49 && col < 49) {
        int dy = col / 7 - r / 7 + 6;
        int dx = col % 7 - r % 7 + 6;
        return sv * SCALE + biasF[(dy * 13 + dx) * 6 + h];
      }
      return -1e30f;  // finite mask: exp -> 0, never NaN
    };

    #pragma unroll
    for (int reg = 0; reg < 4; ++reg) {
      int r = qrow + g * 4 + reg;          // query row this lane holds
      float v0 = logit(s0[reg], c, r);
      float v1 = logit(s1[reg], 16 + c, r);
      float v2 = logit(s2[reg], 32 + c, r);
      float v3 = logit(s3[reg], 48 + c, r);
      float mx = fmaxf(fmaxf(v0, v1), fmaxf(v2, v3));
      mx = fmaxf(mx, __shfl_xor(mx, 1));
      mx = fmaxf(mx, __shfl_xor(mx, 2));
      mx = fmaxf(mx, __shfl_xor(mx, 4));
      mx = fmaxf(mx, __shfl_xor(mx, 8));   // row lives in one 16-lane group
      v0 = __expf(v0 - mx); v1 = __expf(v1 - mx); v2 = __expf(v2 - mx); v3 = __expf(v3 - mx);
      float sm = v0 + v1 + v2 + v3;
      sm += __shfl_xor(sm, 1); sm += __shfl_xor(sm, 2);
      sm += __shfl_xor(sm, 4); sm += __shfl_xor(sm, 8);
      float inv = 1.0f / sm;               // sm >= 1 always
      int pr = (g * 4 + reg) * 72;
      Psw[pr + c]      = f2bf(v0 * inv);
      Psw[pr + 16 + c] = f2bf(v1 * inv);
      Psw[pr + 32 + c] = f2bf(v2 * inv);
      Psw[pr + 48 + c] = f2bf(v3 * inv);
    }

    // PV: A = P (wave-private LDS, same-wave DS ordering), B = V from Vt[d][token]
    f32x4 o0 = z, o1 = z;
    #pragma unroll
    for (int ks = 0; ks < 2; ++ks) {       // K = 64 tokens (49 real, rest zero-prob/zero-V)
      int ko = ks * 32 + g * 8;
      bf16x8 ap  = *(const bf16x8*)(Psw + c * 72 + ko);
      bf16x8 bv0 = *(const bf16x8*)(Vt + (h * 32 + c) * 72 + ko);
      bf16x8 bv1 = *(const bf16x8*)(Vt + (h * 32 + 16 + c) * 72 + ko);
      o0 = __builtin_amdgcn_mfma_f32_16x16x32_bf16(ap, bv0, o0, 0, 0, 0);
      o1 = __builtin_amdgcn_mfma_f32_16x16x32_bf16(ap, bv1, o1, 0, 0, 0);
    }
    int rb = qrow + g * 4;
    #pragma unroll
    for (int r = 0; r < 4; ++r) {          // attn-out -> Xs (X no longer needed)
      Xs[(rb + r) * 200 + h * 32 + c]      = f2bf(o0[r]);
      Xs[(rb + r) * 200 + h * 32 + 16 + c] = f2bf(o1[r]);
    }
  }
  __syncthreads();

  // ---- Phase C: Y = attnout @ Wo + bo, 3 chunks of 64 cols ----
  for (int nc = 0; nc < 3; ++nc) {
    const unsigned short* Wg = WoT + nc * (64 * 192);
    #pragma unroll
    for (int jj = 0; jj < 3; ++jj) {
      int j = tid + jj * 512;
      uint4 v = ((const uint4*)Wg)[j];
      int row = j / 24, kc = j % 24;
      *(uint4*)(WtC + row * 200 + kc * 8) = v;
    }
    __syncthreads();

    f32x4 a0 = {0.f, 0.f, 0.f, 0.f}, a1 = {0.f, 0.f, 0.f, 0.f};
    const unsigned short* ar = Xs + (qrow + c) * 200;
    const unsigned short* b0 = WtC + (half * 32 + c) * 200;
    const unsigned short* b1 = b0 + 16 * 200;
    #pragma unroll
    for (int ks = 0; ks < 6; ++ks) {
      int ko = ks * 32 + g * 8;
      bf16x8 av = *(const bf16x8*)(ar + ko);
      a0 = __builtin_amdgcn_mfma_f32_16x16x32_bf16(av, *(const bf16x8*)(b0 + ko), a0, 0, 0, 0);
      a1 = __builtin_amdgcn_mfma_f32_16x16x32_bf16(av, *(const bf16x8*)(b1 + ko), a1, 0, 0, 0);
    }
    float* og = out + (size_t)wb * 9408;
    #pragma unroll
    for (int i = 0; i < 2; ++i) {
      f32x4 acc = i ? a1 : a0;
      int gcol = nc * 64 + half * 32 + i * 16 + c;
      float bb = bo[gcol];
      #pragma unroll
      for (int r = 0; r < 4; ++r) {
        int rr = qrow + g * 4 + r;
        if (rr < 49) og[rr * 192 + gcol] = acc[r] + bb;
      }
    }
    __syncthreads();
  }
}

extern "C" void kernel_launch(void* const* d_in, const int* in_sizes, int n_in,
                              void* d_out, int out_size, void* d_ws, size_t ws_size,
                              hipStream_t stream) {
  const float* X    = (const float*)d_in[0];
  const float* Wqkv = (const float*)d_in[1];
  const float* bqkv = (const float*)d_in[2];
  const float* Wo   = (const float*)d_in[3];
  const float* bo   = (const float*)d_in[4];
  const float* btab = (const float*)d_in[5];

  unsigned short* WqkvT = (unsigned short*)d_ws;        // 576*192 bf16
  unsigned short* WoT   = WqkvT + 576 * 192;            // 192*192 bf16 (total 295 KB of ws)

  wprep<<<432, 256, 0, stream>>>(Wqkv, Wo, WqkvT, WoT);
  winmsa<<<4096, 512, 0, stream>>>(X, WqkvT, bqkv, WoT, bo, btab, (float*)d_out);
}